// Round 5
// baseline (408.910 us; speedup 1.0000x reference)
//
#include <hip/hip_runtime.h>
#include <hip/hip_bf16.h>
#include <stdint.h>

// out = (QK^T/sqrt(d))V = Q (K^T V)/sqrt(d)   (no softmax in ref)
// F = Wq^T Wk (batch-indep);  G = x^T x;  H = F G;  Pt = [Wv H^T + rank-1]/sqrt(d)
// out = x Pt^T + 1 r^T,  r = M^T bq  (vec role).
// 5 launches: preamble, [G|F], [H|vec], Pt, final.  ws ~74.3 MB.

#define BM 128
#define BN 128
#define BK 64

typedef __attribute__((ext_vector_type(8))) short short8;
typedef __attribute__((ext_vector_type(8))) unsigned short ushort8;
typedef __attribute__((ext_vector_type(4))) float f32x4;
typedef __attribute__((address_space(3))) void lds_void;
typedef const __attribute__((address_space(1))) void gmem_void;

__device__ __forceinline__ unsigned short f2bf(float f) {
  union { float f; unsigned u; } v; v.f = f;
  unsigned r = v.u + 0x7fff + ((v.u >> 16) & 1);   // RNE
  return (unsigned short)(r >> 16);
}
__device__ __forceinline__ float bf2f(unsigned short u) {
  union { unsigned u; float f; } v; v.u = ((unsigned)u) << 16; return v.f;
}

// ---------------- preamble: x->xt,xb,col-partials; Wq^T,Wk^T,Wv casts -------
__global__ __launch_bounds__(256) void preamble(
    const float* __restrict__ x, const float* __restrict__ Wq,
    const float* __restrict__ Wk, const float* __restrict__ Wv,
    unsigned short* __restrict__ xb, unsigned short* __restrict__ xt,
    unsigned short* __restrict__ wqtb, unsigned short* __restrict__ wktb,
    unsigned short* __restrict__ wvb, float* __restrict__ partials)
{
  const int bid = blockIdx.x;
  const int tid = threadIdx.x;
  if (bid < 6144) {                       // x role: 64l x 32d tile
    __shared__ float tile[64][33];
    __shared__ float pt[8][32];
    const int z = bid / 768, rem = bid % 768;
    const int l0 = (rem / 24) * 64, d0 = (rem % 24) * 32;
    const int tx = tid & 31, ty = tid >> 5;
    const float* xz = x + ((long)z * 2048 + l0) * 768 + d0;
    unsigned short* xbz = xb + ((long)z * 2048 + l0) * 768 + d0;
    float colacc = 0.f;
#pragma unroll
    for (int i = 0; i < 8; ++i) {
      float v = xz[(long)(i * 8 + ty) * 768 + tx];
      tile[i * 8 + ty][tx] = v;
      xbz[(long)(i * 8 + ty) * 768 + tx] = f2bf(v);
      colacc += v;
    }
    pt[ty][tx] = colacc;
    __syncthreads();
    unsigned short* xtz = xt + ((long)z * 768 + d0) * 2048 + l0;
#pragma unroll
    for (int i = 0; i < 4; ++i) {
      int d = i * 8 + ty;
      ushort2 o; o.x = f2bf(tile[2 * tx][d]); o.y = f2bf(tile[2 * tx + 1][d]);
      *(ushort2*)(xtz + (long)d * 2048 + 2 * tx) = o;
    }
    if (ty == 0) {
      float s = 0.f;
#pragma unroll
      for (int t = 0; t < 8; ++t) s += pt[t][tx];
      partials[((long)z * 768 + d0 + tx) * 32 + (l0 >> 6)] = s;
    }
  } else if (bid < 7296) {                // weight transpose (wq, wk)
    __shared__ float tl[32][33];
    int t = bid - 6144;
    const float* W = (t < 576) ? Wq : Wk;
    unsigned short* O = (t < 576) ? wqtb : wktb;
    t = (t >= 576) ? t - 576 : t;
    const int r0 = (t / 24) * 32, c0 = (t % 24) * 32;
    const int tx = tid & 31, ty = tid >> 5;
    for (int i = ty; i < 32; i += 8) tl[i][tx] = W[(long)(r0 + i) * 768 + c0 + tx];
    __syncthreads();
    for (int i = ty; i < 32; i += 8) O[(long)(c0 + i) * 768 + r0 + tx] = f2bf(tl[tx][i]);
  } else {                                // wv cast, 288 blocks x 2048 elems
    const int t = bid - 7296;
    const long i = ((long)t * 256 + tid) * 8;
    float4 v0 = *(const float4*)(Wv + i);
    float4 v1 = *(const float4*)(Wv + i + 4);
    unsigned short o[8];
    o[0] = f2bf(v0.x); o[1] = f2bf(v0.y); o[2] = f2bf(v0.z); o[3] = f2bf(v0.w);
    o[4] = f2bf(v1.x); o[5] = f2bf(v1.y); o[6] = f2bf(v1.z); o[7] = f2bf(v1.w);
    *(ushort8*)(wvb + i) = *(ushort8*)o;
  }
}

// ------------- GEMM core: BK=64, 2-phase, T2 XOR-swizzled LDS ---------------
// C[m,n] = scale*sum_k A[m,k]*B[n,k] (+bias)
// BIAS_MODE: 0 none; 1: += bias[z*bias_bs+col];
//            3: v += scale*(bias[row]*(b2[z*768+col]+2048*b4[col]) + b3[z*768+row]*b4[col])
template<int BIAS_MODE, int OUT_BF16>
__device__ __forceinline__ void gemm_core(
    int z, int tt, int nbx,
    unsigned short* __restrict__ As, unsigned short* __restrict__ Bs,  // LDS [2][BM*BK]
    const unsigned short* __restrict__ A, const unsigned short* __restrict__ B,
    const float* __restrict__ bias, const float* __restrict__ b2,
    const float* __restrict__ b3, const float* __restrict__ b4,
    void* __restrict__ Cv,
    int K, int lda, int ldb, int ldc,
    long a_bs, long b_bs, long c_bs, long bias_bs, float scale)
{
  const int tid  = threadIdx.x;
  const int wid  = tid >> 6;
  const int lane = tid & 63;
  const long bm  = (long)(tt / nbx) * BM;
  const long bn  = (long)(tt % nbx) * BN;
  const unsigned short* Ab = A + (long)z * a_bs;
  const unsigned short* Bb = B + (long)z * b_bs;

  f32x4 acc[4][4];
#pragma unroll
  for (int r = 0; r < 4; ++r)
#pragma unroll
    for (int c = 0; c < 4; ++c) acc[r][c] = (f32x4){0.f, 0.f, 0.f, 0.f};

  const int srow = lane >> 3;                    // row within 8-row group
  const int scol = (((lane & 7) ^ srow)) * 8;    // pre-swizzled source chunk
  const int fr   = lane & 15;
  const int xr   = lane & 7;                     // row&7 for read-side XOR
  const int kq   = lane >> 4;                    // 0..3

#define STAGE(p, k0) do { \
  _Pragma("unroll") \
  for (int j_ = 0; j_ < 4; ++j_) { \
    const int r_ = wid * 32 + j_ * 8; \
    const unsigned short* ga_ = Ab + (bm + r_ + srow) * (long)lda + (k0) + scol; \
    __builtin_amdgcn_global_load_lds((gmem_void*)ga_, (lds_void*)(As + (p) * BM * BK + r_ * BK), 16, 0, 0); \
    const unsigned short* gb_ = Bb + (bn + r_ + srow) * (long)ldb + (k0) + scol; \
    __builtin_amdgcn_global_load_lds((gmem_void*)gb_, (lds_void*)(Bs + (p) * BN * BK + r_ * BK), 16, 0, 0); \
  } } while (0)

  const int nt = K / BK;
  STAGE(0, 0);
  __syncthreads();

  for (int t = 0; t < nt; ++t) {
    const int p = t & 1;
    if (t + 1 < nt) STAGE(p ^ 1, (t + 1) * BK);   // issue next-tile loads first
    __builtin_amdgcn_s_setprio(1);
#pragma unroll
    for (int kk = 0; kk < 2; ++kk) {
      short8 af[4], bfr[4];
#pragma unroll
      for (int r = 0; r < 4; ++r) {
        const int row = (wid >> 1) * 64 + r * 16 + fr;
        af[r] = *(const short8*)(As + p * BM * BK + row * BK + (((kk * 4 + kq) ^ xr) << 3));
      }
#pragma unroll
      for (int c = 0; c < 4; ++c) {
        const int row = (wid & 1) * 64 + c * 16 + fr;
        bfr[c] = *(const short8*)(Bs + p * BN * BK + row * BK + (((kk * 4 + kq) ^ xr) << 3));
      }
#pragma unroll
      for (int r = 0; r < 4; ++r)
#pragma unroll
        for (int c = 0; c < 4; ++c)
          acc[r][c] = __builtin_amdgcn_mfma_f32_16x16x32_bf16(af[r], bfr[c], acc[r][c], 0, 0, 0);
    }
    __builtin_amdgcn_s_setprio(0);
    if (t + 1 < nt) __syncthreads();   // drains stage t+1 (vmcnt) + WAR on LDS
  }
#undef STAGE

  const int wr  = (wid >> 1) * 64;
  const int wc  = (wid & 1) * 64;
  const int cr0 = (lane >> 4) * 4;
  const int cc  = lane & 15;
#pragma unroll
  for (int r = 0; r < 4; ++r)
#pragma unroll
    for (int c = 0; c < 4; ++c)
#pragma unroll
      for (int j = 0; j < 4; ++j) {
        long row = bm + wr + r * 16 + cr0 + j;
        long col = bn + wc + c * 16 + cc;
        float v = acc[r][c][j] * scale;
        if (BIAS_MODE == 1) v += bias[z * bias_bs + col];
        else if (BIAS_MODE == 3)
          v += scale * (bias[row] * (b2[z * 768 + col] + 2048.0f * b4[col])
                        + b3[z * 768 + row] * b4[col]);
        long off = (long)z * c_bs + row * (long)ldc + col;
        if (OUT_BF16) ((unsigned short*)Cv)[off] = f2bf(v);
        else          ((float*)Cv)[off] = v;
      }
}

// generic wrapper: z = bid&7, tt = bid>>3
template<int BIAS_MODE, int OUT_BF16>
__global__ __launch_bounds__(256, 2) void gemm_k(
    const unsigned short* A, const unsigned short* B, const float* bias,
    const float* b2, const float* b3, const float* b4, void* Cv,
    int K, int lda, int ldb, int ldc, int nbx,
    long a_bs, long b_bs, long c_bs, long bias_bs, float scale)
{
  __shared__ unsigned short As[2][BM * BK];
  __shared__ unsigned short Bs[2][BN * BK];
  gemm_core<BIAS_MODE, OUT_BF16>(blockIdx.x & 7, blockIdx.x >> 3, nbx,
      &As[0][0], &Bs[0][0], A, B, bias, b2, b3, b4, Cv,
      K, lda, ldb, ldc, a_bs, b_bs, c_bs, bias_bs, scale);
}

// G (288 blocks) + F (36 blocks) fused
__global__ __launch_bounds__(256, 2) void gf_k(
    const unsigned short* xt, unsigned short* G,
    const unsigned short* wqtb, const unsigned short* wktb, unsigned short* F)
{
  __shared__ unsigned short As[2][BM * BK];
  __shared__ unsigned short Bs[2][BN * BK];
  if (blockIdx.x < 288)
    gemm_core<0, 1>(blockIdx.x & 7, blockIdx.x >> 3, 6, &As[0][0], &Bs[0][0],
        xt, xt, nullptr, nullptr, nullptr, nullptr, G,
        2048, 2048, 2048, 768, 768L * 2048, 768L * 2048, 768L * 768, 0, 1.0f);
  else
    gemm_core<0, 1>(0, blockIdx.x - 288, 6, &As[0][0], &Bs[0][0],
        wqtb, wktb, nullptr, nullptr, nullptr, nullptr, F,
        768, 768, 768, 768, 0, 0, 0, 0, 1.0f);
}

// vec role: s, c1=Wk^T bq, a2=Wq^T bk, a1=F s, w=Wv s, g=G c1, r
__device__ void vec_role(int z,
    const unsigned short* __restrict__ wktb, const unsigned short* __restrict__ wqtb,
    const unsigned short* __restrict__ Fb, const unsigned short* __restrict__ Gz,
    const float* __restrict__ Wv, const float* __restrict__ bq,
    const float* __restrict__ bk, const float* __restrict__ bv,
    const float* __restrict__ partials, float* __restrict__ sv,
    float* __restrict__ a1v, float* __restrict__ a2v,
    float* __restrict__ wvv, float* __restrict__ rv)
{
  __shared__ float s_l[768], c1_l[768], g_l[768], w_l[768];
  __shared__ float red1[256], red2[256];
  const int tid = threadIdx.x;
  const float inv_sqrt_d = 0.036084391824351615f;
  for (int rr = tid; rr < 768; rr += 256) {
    const float* pp = partials + ((long)z * 768 + rr) * 32;
    float s = 0.f;
#pragma unroll
    for (int j = 0; j < 32; ++j) s += pp[j];
    s_l[rr] = s; sv[z * 768 + rr] = s;
  }
  __syncthreads();
  for (int rr = tid; rr < 768; rr += 256) {
    float c1 = 0.f, a2 = 0.f, a1 = 0.f, w = 0.f;
    const unsigned short* rk = wktb + (long)rr * 768;
    const unsigned short* rq = wqtb + (long)rr * 768;
    const unsigned short* rf = Fb + (long)rr * 768;
    const float* rw = Wv + (long)rr * 768;
    for (int i = 0; i < 96; ++i) {
      short8 vk = *(const short8*)(rk + i * 8);
      short8 vq = *(const short8*)(rq + i * 8);
      short8 vf = *(const short8*)(rf + i * 8);
#pragma unroll
      for (int e = 0; e < 8; ++e) {
        int idx = i * 8 + e;
        c1 += bf2f((unsigned short)vk[e]) * bq[idx];
        a2 += bf2f((unsigned short)vq[e]) * bk[idx];
        a1 += bf2f((unsigned short)vf[e]) * s_l[idx];
      }
    }
    for (int i = 0; i < 192; ++i) {
      float4 v = *(const float4*)(rw + i * 4);
      w += v.x * s_l[i * 4] + v.y * s_l[i * 4 + 1] + v.z * s_l[i * 4 + 2] + v.w * s_l[i * 4 + 3];
    }
    c1_l[rr] = c1; w_l[rr] = w;
    a1v[z * 768 + rr] = a1; a2v[rr] = a2; wvv[z * 768 + rr] = w;
  }
  __syncthreads();
  float p1 = 0.f, p2 = 0.f;
  for (int rr = tid; rr < 768; rr += 256) { p1 += c1_l[rr] * s_l[rr]; p2 += bq[rr] * bk[rr]; }
  red1[tid] = p1; red2[tid] = p2;
  for (int rr = tid; rr < 768; rr += 256) {
    const unsigned short* rg = Gz + (long)rr * 768;
    float g = 0.f;
    for (int i = 0; i < 96; ++i) {
      short8 vg = *(const short8*)(rg + i * 8);
#pragma unroll
      for (int e = 0; e < 8; ++e) g += bf2f((unsigned short)vg[e]) * c1_l[i * 8 + e];
    }
    g_l[rr] = g;
  }
  __syncthreads();
  for (int st = 128; st > 0; st >>= 1) {
    if (tid < st) { red1[tid] += red1[tid + st]; red2[tid] += red2[tid + st]; }
    __syncthreads();
  }
  const float cs = red1[0], bb = red2[0];
  for (int rr = tid; rr < 768; rr += 256) {
    const float* rw = Wv + (long)rr * 768;
    float a = 0.f;
    for (int i = 0; i < 192; ++i) {
      float4 v = *(const float4*)(rw + i * 4);
      a += v.x * g_l[i * 4] + v.y * g_l[i * 4 + 1] + v.z * g_l[i * 4 + 2] + v.w * g_l[i * 4 + 3];
    }
    rv[z * 768 + rr] = inv_sqrt_d * (a + cs * bv[rr] + bb * (w_l[rr] + 2048.0f * bv[rr]));
  }
}

// H = F G (288 blocks) + vec (8 blocks)
__global__ __launch_bounds__(256, 2) void hv_k(
    const unsigned short* Fb, const unsigned short* G, unsigned short* H,
    const unsigned short* wktb, const unsigned short* wqtb,
    const float* Wv, const float* bq, const float* bk, const float* bv,
    const float* partials, float* sv, float* a1v, float* a2v, float* wvv, float* rv)
{
  if (blockIdx.x < 288) {
    __shared__ unsigned short As[2][BM * BK];
    __shared__ unsigned short Bs[2][BN * BK];
    gemm_core<0, 1>(blockIdx.x & 7, blockIdx.x >> 3, 6, &As[0][0], &Bs[0][0],
        Fb, G, nullptr, nullptr, nullptr, nullptr, H,
        768, 768, 768, 768, 0, 768L * 768, 768L * 768, 0, 1.0f);
  } else {
    const int z = blockIdx.x - 288;
    vec_role(z, wktb, wqtb, Fb, G + (long)z * 768 * 768, Wv, bq, bk, bv,
             partials, sv, a1v, a2v, wvv, rv);
  }
}

extern "C" void kernel_launch(void* const* d_in, const int* in_sizes, int n_in,
                              void* d_out, int out_size, void* d_ws, size_t ws_size,
                              hipStream_t stream) {
  const float* x  = (const float*)d_in[0];
  const float* Wq = (const float*)d_in[1];
  const float* bq = (const float*)d_in[2];
  const float* Wk = (const float*)d_in[3];
  const float* bk = (const float*)d_in[4];
  const float* Wv = (const float*)d_in[5];
  const float* bv = (const float*)d_in[6];
  float* out = (float*)d_out;

  const int Bsz = 8, L = 2048, D = 768;
  const long xN = (long)Bsz * L * D;       // 12,582,912
  const long wN = (long)D * D;             // 589,824
  const long D2 = wN;

  char* ws = (char*)d_ws;
  unsigned short* xt   = (unsigned short*)ws; ws += xN * 2;             // 25.2 MB
  unsigned short* xb   = (unsigned short*)ws; ws += xN * 2;             // 25.2 MB
  unsigned short* wqtb = (unsigned short*)ws; ws += wN * 2;
  unsigned short* wktb = (unsigned short*)ws; ws += wN * 2;
  unsigned short* wvb  = (unsigned short*)ws; ws += wN * 2;
  unsigned short* Fb   = (unsigned short*)ws; ws += wN * 2;
  unsigned short* regA = (unsigned short*)ws; ws += (long)Bsz * D2 * 2; // G, later Pt
  unsigned short* regB = (unsigned short*)ws; ws += (long)Bsz * D2 * 2; // H
  float* partials = (float*)ws; ws += (long)Bsz * D * 32 * 4;
  float* sv  = (float*)ws; ws += (long)Bsz * D * 4;
  float* a1v = (float*)ws; ws += (long)Bsz * D * 4;
  float* a2v = (float*)ws; ws += (long)D * 4;
  float* wvv = (float*)ws; ws += (long)Bsz * D * 4;
  float* rv  = (float*)ws; ws += (long)Bsz * D * 4;   // total ~74.3 MB

  const float inv_sqrt_d = 0.036084391824351615f;  // 1/sqrt(768)
  dim3 blk(256);

  // 1) preamble: xt, xb, col-partials, wqt, wkt, wv
  preamble<<<dim3(7584), blk, 0, stream>>>(x, Wq, Wk, Wv, xb, xt, wqtb, wktb, wvb, partials);

  // 2) G[z] = xt xt^T (K=2048) -> regA ; F = wqt wkt^T -> Fb
  gf_k<<<dim3(324), blk, 0, stream>>>(xt, regA, wqtb, wktb, Fb);

  // 3) H[z] = F G[z] -> regB ; vec -> sv,a1v,a2v,wvv,rv
  hv_k<<<dim3(296), blk, 0, stream>>>(Fb, regA, regB, wktb, wqtb,
                                      Wv, bq, bk, bv, partials, sv, a1v, a2v, wvv, rv);

  // 4) Pt[z] = [Wv H^T + bv(a1+2048 a2)^T + w a2^T]/sqrt(d) -> regA
  gemm_k<3, 1><<<dim3(288), blk, 0, stream>>>(
      wvb, regB, bv, a1v, wvv, a2v, regA,
      D, D, D, D, 6, 0, D2, D2, 0, inv_sqrt_d);

  // 5) out[z] = xb[z] Pt[z]^T + r[z]
  gemm_k<1, 0><<<dim3(768), blk, 0, stream>>>(
      xb, regA, rv, nullptr, nullptr, nullptr, out,
      D, D, D, D, 6, (long)L * D, D2, (long)L * D, (long)D, 1.0f);

  (void)in_sizes; (void)n_in; (void)out_size; (void)ws_size;
}

// Round 6
// 209.860 us; speedup vs baseline: 1.9485x; 1.9485x over previous
//
#include <hip/hip_runtime.h>
#include <hip/hip_bf16.h>
#include <stdint.h>

// out = (QK^T/sqrt(d))V = Q (K^T V)/sqrt(d)   (no softmax in ref)
// F = Wq^T Wk;  G = x^T x;  H = F G;  Pt = [Wv H^T + bv a1^T + w a2^T + L bv a2^T]/sqrt(d)
// r[z,o] = [Wv·g + cs bv + bb (w + L bv)]/sqrt(d);  out = xb Pt^T + 1 r^T
// c1=Wk^T bq, a2=Wq^T bk, s=colsum(x), a1=F s, w=Wv s, g=G c1, cs=c1·s, bb=bq·bk
// Round-5 lesson: vec work must be wave-per-row parallel, not 8 serial blocks.

#define BM 128
#define BN 128
#define BK 64

typedef __attribute__((ext_vector_type(8))) short short8;
typedef __attribute__((ext_vector_type(8))) unsigned short ushort8;
typedef __attribute__((ext_vector_type(4))) float f32x4;
typedef __attribute__((address_space(3))) void lds_void;
typedef const __attribute__((address_space(1))) void gmem_void;

__device__ __forceinline__ unsigned short f2bf(float f) {
  union { float f; unsigned u; } v; v.f = f;
  unsigned r = v.u + 0x7fff + ((v.u >> 16) & 1);   // RNE
  return (unsigned short)(r >> 16);
}
__device__ __forceinline__ float bf2f(unsigned short u) {
  union { unsigned u; float f; } v; v.u = ((unsigned)u) << 16; return v.f;
}
__device__ __forceinline__ float wave_red(float a) {
#pragma unroll
  for (int off = 32; off; off >>= 1) a += __shfl_down(a, off);
  return a;
}

// ---------------- preamble: x->xt,xb,col-partials; Wq^T,Wk^T,Wv casts -------
__global__ __launch_bounds__(256) void preamble(
    const float* __restrict__ x, const float* __restrict__ Wq,
    const float* __restrict__ Wk, const float* __restrict__ Wv,
    unsigned short* __restrict__ xb, unsigned short* __restrict__ xt,
    unsigned short* __restrict__ wqtb, unsigned short* __restrict__ wktb,
    unsigned short* __restrict__ wvb, float* __restrict__ partials)
{
  const int bid = blockIdx.x;
  const int tid = threadIdx.x;
  if (bid < 6144) {                       // x role: 64l x 32d tile
    __shared__ float tile[64][33];
    __shared__ float pt[8][32];
    const int z = bid / 768, rem = bid % 768;
    const int l0 = (rem / 24) * 64, d0 = (rem % 24) * 32;
    const int tx = tid & 31, ty = tid >> 5;
    const float* xz = x + ((long)z * 2048 + l0) * 768 + d0;
    unsigned short* xbz = xb + ((long)z * 2048 + l0) * 768 + d0;
    float colacc = 0.f;
#pragma unroll
    for (int i = 0; i < 8; ++i) {
      float v = xz[(long)(i * 8 + ty) * 768 + tx];
      tile[i * 8 + ty][tx] = v;
      xbz[(long)(i * 8 + ty) * 768 + tx] = f2bf(v);
      colacc += v;
    }
    pt[ty][tx] = colacc;
    __syncthreads();
    unsigned short* xtz = xt + ((long)z * 768 + d0) * 2048 + l0;
#pragma unroll
    for (int i = 0; i < 4; ++i) {
      int d = i * 8 + ty;
      ushort2 o; o.x = f2bf(tile[2 * tx][d]); o.y = f2bf(tile[2 * tx + 1][d]);
      *(ushort2*)(xtz + (long)d * 2048 + 2 * tx) = o;
    }
    if (ty == 0) {
      float s = 0.f;
#pragma unroll
      for (int t = 0; t < 8; ++t) s += pt[t][tx];
      partials[((long)z * 768 + d0 + tx) * 32 + (l0 >> 6)] = s;
    }
  } else if (bid < 7296) {                // weight transpose (wq, wk)
    __shared__ float tl[32][33];
    int t = bid - 6144;
    const float* W = (t < 576) ? Wq : Wk;
    unsigned short* O = (t < 576) ? wqtb : wktb;
    t = (t >= 576) ? t - 576 : t;
    const int r0 = (t / 24) * 32, c0 = (t % 24) * 32;
    const int tx = tid & 31, ty = tid >> 5;
    for (int i = ty; i < 32; i += 8) tl[i][tx] = W[(long)(r0 + i) * 768 + c0 + tx];
    __syncthreads();
    for (int i = ty; i < 32; i += 8) O[(long)(c0 + i) * 768 + r0 + tx] = f2bf(tl[tx][i]);
  } else {                                // wv cast, 288 blocks x 2048 elems
    const int t = bid - 7296;
    const long i = ((long)t * 256 + tid) * 8;
    float4 v0 = *(const float4*)(Wv + i);
    float4 v1 = *(const float4*)(Wv + i + 4);
    unsigned short o[8];
    o[0] = f2bf(v0.x); o[1] = f2bf(v0.y); o[2] = f2bf(v0.z); o[3] = f2bf(v0.w);
    o[4] = f2bf(v1.x); o[5] = f2bf(v1.y); o[6] = f2bf(v1.z); o[7] = f2bf(v1.w);
    *(ushort8*)(wvb + i) = *(ushort8*)o;
  }
}

// ------------- GEMM core: BK=64, 2-phase, T2 XOR-swizzled LDS ---------------
template<int BIAS_MODE, int OUT_BF16>
__device__ __forceinline__ void gemm_core(
    int z, int tt, int nbx,
    unsigned short* __restrict__ As, unsigned short* __restrict__ Bs,
    const unsigned short* __restrict__ A, const unsigned short* __restrict__ B,
    const float* __restrict__ bias, const float* __restrict__ b2,
    const float* __restrict__ b3, const float* __restrict__ b4,
    void* __restrict__ Cv,
    int K, int lda, int ldb, int ldc,
    long a_bs, long b_bs, long c_bs, long bias_bs, float scale)
{
  const int tid  = threadIdx.x;
  const int wid  = tid >> 6;
  const int lane = tid & 63;
  const long bm  = (long)(tt / nbx) * BM;
  const long bn  = (long)(tt % nbx) * BN;
  const unsigned short* Ab = A + (long)z * a_bs;
  const unsigned short* Bb = B + (long)z * b_bs;

  f32x4 acc[4][4];
#pragma unroll
  for (int r = 0; r < 4; ++r)
#pragma unroll
    for (int c = 0; c < 4; ++c) acc[r][c] = (f32x4){0.f, 0.f, 0.f, 0.f};

  const int srow = lane >> 3;
  const int scol = (((lane & 7) ^ srow)) * 8;
  const int fr   = lane & 15;
  const int xr   = lane & 7;
  const int kq   = lane >> 4;

#define STAGE(p, k0) do { \
  _Pragma("unroll") \
  for (int j_ = 0; j_ < 4; ++j_) { \
    const int r_ = wid * 32 + j_ * 8; \
    const unsigned short* ga_ = Ab + (bm + r_ + srow) * (long)lda + (k0) + scol; \
    __builtin_amdgcn_global_load_lds((gmem_void*)ga_, (lds_void*)(As + (p) * BM * BK + r_ * BK), 16, 0, 0); \
    const unsigned short* gb_ = Bb + (bn + r_ + srow) * (long)ldb + (k0) + scol; \
    __builtin_amdgcn_global_load_lds((gmem_void*)gb_, (lds_void*)(Bs + (p) * BN * BK + r_ * BK), 16, 0, 0); \
  } } while (0)

  const int nt = K / BK;
  STAGE(0, 0);
  __syncthreads();

  for (int t = 0; t < nt; ++t) {
    const int p = t & 1;
    if (t + 1 < nt) STAGE(p ^ 1, (t + 1) * BK);
    __builtin_amdgcn_s_setprio(1);
#pragma unroll
    for (int kk = 0; kk < 2; ++kk) {
      short8 af[4], bfr[4];
#pragma unroll
      for (int r = 0; r < 4; ++r) {
        const int row = (wid >> 1) * 64 + r * 16 + fr;
        af[r] = *(const short8*)(As + p * BM * BK + row * BK + (((kk * 4 + kq) ^ xr) << 3));
      }
#pragma unroll
      for (int c = 0; c < 4; ++c) {
        const int row = (wid & 1) * 64 + c * 16 + fr;
        bfr[c] = *(const short8*)(Bs + p * BN * BK + row * BK + (((kk * 4 + kq) ^ xr) << 3));
      }
#pragma unroll
      for (int r = 0; r < 4; ++r)
#pragma unroll
        for (int c = 0; c < 4; ++c)
          acc[r][c] = __builtin_amdgcn_mfma_f32_16x16x32_bf16(af[r], bfr[c], acc[r][c], 0, 0, 0);
    }
    __builtin_amdgcn_s_setprio(0);
    if (t + 1 < nt) __syncthreads();
  }
#undef STAGE

  const int wr  = (wid >> 1) * 64;
  const int wc  = (wid & 1) * 64;
  const int cr0 = (lane >> 4) * 4;
  const int cc  = lane & 15;
#pragma unroll
  for (int r = 0; r < 4; ++r)
#pragma unroll
    for (int c = 0; c < 4; ++c)
#pragma unroll
      for (int j = 0; j < 4; ++j) {
        long row = bm + wr + r * 16 + cr0 + j;
        long col = bn + wc + c * 16 + cc;
        float v = acc[r][c][j] * scale;
        if (BIAS_MODE == 1) v += bias[z * bias_bs + col];
        else if (BIAS_MODE == 3)
          v += scale * (bias[row] * (b2[z * 768 + col] + 2048.0f * b4[col])
                        + b3[z * 768 + row] * b4[col]);
        long off = (long)z * c_bs + row * (long)ldc + col;
        if (OUT_BF16) ((unsigned short*)Cv)[off] = f2bf(v);
        else          ((float*)Cv)[off] = v;
      }
}

// ---- launch 2: G (0..287) + F (288..323) + c1,a2 (324..347) + s (348..355) --
__global__ __launch_bounds__(256, 2) void gf_k(
    const unsigned short* xt, unsigned short* G,
    const unsigned short* wqtb, const unsigned short* wktb, unsigned short* F,
    const float* bq, const float* bk, const float* partials,
    float* c1v, float* a2v, float* sv)
{
  const int bid = blockIdx.x, tid = threadIdx.x;
  if (bid < 288) {
    __shared__ unsigned short As[2][BM * BK];
    __shared__ unsigned short Bs[2][BN * BK];
    gemm_core<0, 1>(bid & 7, bid >> 3, 6, &As[0][0], &Bs[0][0],
        xt, xt, nullptr, nullptr, nullptr, nullptr, G,
        2048, 2048, 2048, 768, 768L * 2048, 768L * 2048, 768L * 768, 0, 1.0f);
  } else if (bid < 324) {
    __shared__ unsigned short As[2][BM * BK];
    __shared__ unsigned short Bs[2][BN * BK];
    gemm_core<0, 1>(0, bid - 288, 6, &As[0][0], &Bs[0][0],
        wqtb, wktb, nullptr, nullptr, nullptr, nullptr, F,
        768, 768, 768, 768, 0, 0, 0, 0, 1.0f);
  } else if (bid < 348) {                 // c1[r]=wkt[r,:]·bq ; a2[r]=wqt[r,:]·bk
    const int wid = tid >> 6, lane = tid & 63;
    const int r0 = (bid - 324) * 32;
#pragma unroll
    for (int mi = 0; mi < 8; ++mi) {
      const int r = r0 + wid * 8 + mi;
      float ac = 0.f, aa = 0.f;
      for (int k = lane; k < 768; k += 64) {
        ac += bf2f(wktb[(long)r * 768 + k]) * bq[k];
        aa += bf2f(wqtb[(long)r * 768 + k]) * bk[k];
      }
      ac = wave_red(ac); aa = wave_red(aa);
      if (lane == 0) { c1v[r] = ac; a2v[r] = aa; }
    }
  } else {                                // s[z,d] from partials
    const int z = bid - 348;
    for (int d = tid; d < 768; d += 256) {
      const float* pp = partials + ((long)z * 768 + d) * 32;
      float s = 0.f;
#pragma unroll
      for (int j = 0; j < 32; ++j) s += pp[j];
      sv[z * 768 + d] = s;
    }
  }
}

// ---- launch 3: H = F·G (0..287) + a1/w/g GEMVs (288..863) -------------------
__global__ __launch_bounds__(256, 2) void hv_k(
    const unsigned short* Fb, const unsigned short* G, unsigned short* H,
    const float* Wv, const float* sv, const float* c1v,
    float* a1v, float* wvv, float* gv)
{
  const int bid = blockIdx.x, tid = threadIdx.x;
  if (bid < 288) {
    __shared__ unsigned short As[2][BM * BK];
    __shared__ unsigned short Bs[2][BN * BK];
    gemm_core<0, 1>(bid & 7, bid >> 3, 6, &As[0][0], &Bs[0][0],
        Fb, G, nullptr, nullptr, nullptr, nullptr, H,
        768, 768, 768, 768, 0, 768L * 768, 768L * 768, 0, 1.0f);
  } else {
    const int t = bid - 288;              // 0..575
    const int type = t / 192, u = t % 192;
    const int z = u / 24, r0 = (u % 24) * 32;
    const int wid = tid >> 6, lane = tid & 63;
#pragma unroll
    for (int mi = 0; mi < 8; ++mi) {
      const int r = r0 + wid * 8 + mi;
      float a = 0.f;
      if (type == 0) {                    // a1[z,r] = F[r,:]·s[z,:]
        for (int k = lane; k < 768; k += 64)
          a += bf2f(Fb[(long)r * 768 + k]) * sv[z * 768 + k];
      } else if (type == 1) {             // w[z,r] = Wv[r,:]·s[z,:]
        for (int k = lane; k < 768; k += 64)
          a += Wv[(long)r * 768 + k] * sv[z * 768 + k];
      } else {                            // g[z,r] = G[z][r,:]·c1
        const unsigned short* Gz = G + (long)z * 768 * 768;
        for (int k = lane; k < 768; k += 64)
          a += bf2f(Gz[(long)r * 768 + k]) * c1v[k];
      }
      a = wave_red(a);
      if (lane == 0) {
        if (type == 0) a1v[z * 768 + r] = a;
        else if (type == 1) wvv[z * 768 + r] = a;
        else gv[z * 768 + r] = a;
      }
    }
  }
}

// ---- launch 4: Pt GEMM (0..287) + r blocks (288..479) -----------------------
__global__ __launch_bounds__(256, 2) void pt_k(
    const unsigned short* wvb, const unsigned short* H, unsigned short* Pt,
    const float* bv, const float* a1v, const float* wvv, const float* a2v,
    const float* Wv, const float* gv, const float* c1v, const float* sv,
    const float* bq, const float* bk, float* rv)
{
  const float inv_sqrt_d = 0.036084391824351615f;
  const int bid = blockIdx.x, tid = threadIdx.x;
  if (bid < 288) {
    __shared__ unsigned short As[2][BM * BK];
    __shared__ unsigned short Bs[2][BN * BK];
    gemm_core<3, 1>(bid & 7, bid >> 3, 6, &As[0][0], &Bs[0][0],
        wvb, H, bv, a1v, wvv, a2v, Pt,
        768, 768, 768, 768, 0, 768L * 768, 768L * 768, 0, inv_sqrt_d);
  } else {
    const int u = bid - 288;              // 0..191
    const int z = u / 24, r0 = (u % 24) * 32;
    const int wid = tid >> 6, lane = tid & 63;
    __shared__ float red1[256], red2[256];
    float p1 = 0.f, p2 = 0.f;
    for (int d = tid; d < 768; d += 256) {
      p1 += c1v[d] * sv[z * 768 + d];
      p2 += bq[d] * bk[d];
    }
    red1[tid] = p1; red2[tid] = p2;
    __syncthreads();
    for (int st = 128; st > 0; st >>= 1) {
      if (tid < st) { red1[tid] += red1[tid + st]; red2[tid] += red2[tid + st]; }
      __syncthreads();
    }
    const float cs = red1[0], bb = red2[0];
#pragma unroll
    for (int mi = 0; mi < 8; ++mi) {
      const int o = r0 + wid * 8 + mi;
      float a = 0.f;
      for (int k = lane; k < 768; k += 64)
        a += Wv[(long)o * 768 + k] * gv[z * 768 + k];
      a = wave_red(a);
      if (lane == 0)
        rv[z * 768 + o] = inv_sqrt_d *
            (a + cs * bv[o] + bb * (wvv[z * 768 + o] + 2048.0f * bv[o]));
    }
  }
}

// ---- launch 5: out = xb·Pt^T + r -------------------------------------------
__global__ __launch_bounds__(256, 2) void final_k(
    const unsigned short* xb, const unsigned short* Pt, const float* rv, float* out)
{
  __shared__ unsigned short As[2][BM * BK];
  __shared__ unsigned short Bs[2][BN * BK];
  gemm_core<1, 0>(blockIdx.x & 7, blockIdx.x >> 3, 6, &As[0][0], &Bs[0][0],
      xb, Pt, rv, nullptr, nullptr, nullptr, out,
      768, 768, 768, 768, 2048L * 768, 768L * 768, 2048L * 768, 768, 1.0f);
}

extern "C" void kernel_launch(void* const* d_in, const int* in_sizes, int n_in,
                              void* d_out, int out_size, void* d_ws, size_t ws_size,
                              hipStream_t stream) {
  const float* x  = (const float*)d_in[0];
  const float* Wq = (const float*)d_in[1];
  const float* bq = (const float*)d_in[2];
  const float* Wk = (const float*)d_in[3];
  const float* bk = (const float*)d_in[4];
  const float* Wv = (const float*)d_in[5];
  const float* bv = (const float*)d_in[6];
  float* out = (float*)d_out;

  const int Bsz = 8, L = 2048, D = 768;
  const long xN = (long)Bsz * L * D;
  const long wN = (long)D * D;
  const long D2 = wN;

  char* ws = (char*)d_ws;
  unsigned short* xt   = (unsigned short*)ws; ws += xN * 2;
  unsigned short* xb   = (unsigned short*)ws; ws += xN * 2;
  unsigned short* wqtb = (unsigned short*)ws; ws += wN * 2;
  unsigned short* wktb = (unsigned short*)ws; ws += wN * 2;
  unsigned short* wvb  = (unsigned short*)ws; ws += wN * 2;
  unsigned short* Fb   = (unsigned short*)ws; ws += wN * 2;
  unsigned short* regA = (unsigned short*)ws; ws += (long)Bsz * D2 * 2;  // G, later Pt
  unsigned short* regB = (unsigned short*)ws; ws += (long)Bsz * D2 * 2;  // H
  float* partials = (float*)ws; ws += (long)Bsz * D * 32 * 4;
  float* sv  = (float*)ws; ws += (long)Bsz * D * 4;
  float* c1v = (float*)ws; ws += (long)D * 4;
  float* a2v = (float*)ws; ws += (long)D * 4;
  float* a1v = (float*)ws; ws += (long)Bsz * D * 4;
  float* wvv = (float*)ws; ws += (long)Bsz * D * 4;
  float* gv  = (float*)ws; ws += (long)Bsz * D * 4;
  float* rv  = (float*)ws; ws += (long)Bsz * D * 4;

  dim3 blk(256);

  preamble<<<dim3(7584), blk, 0, stream>>>(x, Wq, Wk, Wv, xb, xt, wqtb, wktb, wvb, partials);

  gf_k<<<dim3(356), blk, 0, stream>>>(xt, regA, wqtb, wktb, Fb,
                                      bq, bk, partials, c1v, a2v, sv);

  hv_k<<<dim3(864), blk, 0, stream>>>(Fb, regA, regB, Wv, sv, c1v, a1v, wvv, gv);

  pt_k<<<dim3(480), blk, 0, stream>>>(wvb, regB, regA, bv, a1v, wvv, a2v,
                                      Wv, gv, c1v, sv, bq, bk, rv);

  final_k<<<dim3(768), blk, 0, stream>>>(xb, regA, rv, out);

  (void)in_sizes; (void)n_in; (void)out_size; (void)ws_size;
}

// Round 7
// 176.176 us; speedup vs baseline: 2.3210x; 1.1912x over previous
//
#include <hip/hip_runtime.h>
#include <hip/hip_bf16.h>
#include <stdint.h>

// out = (QK^T/sqrt(d))V = Q (K^T V)/sqrt(d)   (no softmax in ref)
// F = Wq^T Wk;  G = x^T x (symmetric);  H = F G;
// Pt = [Wv H^T + bv a1^T + w a2^T + L bv a2^T]/sqrt(d)
// r[z,o] = [Wv·g + cs bv + bb (w + L bv)]/sqrt(d);  out = xb Pt^T + 1 r^T
// c1=Wk^T bq, a2=Wq^T bk, s=colsum(x), a1=F s, w=Wv s, g=G c1, cs=c1·s, bb=bq·bk
// Round-6 lesson: hipcc does NOT union branch-scoped __shared__ — declare once.

#define BM 128
#define BN 128
#define BK 64

typedef __attribute__((ext_vector_type(8))) short short8;
typedef __attribute__((ext_vector_type(8))) unsigned short ushort8;
typedef __attribute__((ext_vector_type(4))) float f32x4;
typedef __attribute__((address_space(3))) void lds_void;
typedef const __attribute__((address_space(1))) void gmem_void;

__device__ __forceinline__ unsigned short f2bf(float f) {
  union { float f; unsigned u; } v; v.f = f;
  unsigned r = v.u + 0x7fff + ((v.u >> 16) & 1);   // RNE
  return (unsigned short)(r >> 16);
}
__device__ __forceinline__ float bf2f(unsigned short u) {
  union { unsigned u; float f; } v; v.u = ((unsigned)u) << 16; return v.f;
}
__device__ __forceinline__ float wave_red(float a) {
#pragma unroll
  for (int off = 32; off; off >>= 1) a += __shfl_down(a, off);
  return a;
}

// ---------------- preamble: x->xt,xb,col-partials; Wq^T,Wk^T,Wv casts -------
__global__ __launch_bounds__(256) void preamble(
    const float* __restrict__ x, const float* __restrict__ Wq,
    const float* __restrict__ Wk, const float* __restrict__ Wv,
    unsigned short* __restrict__ xb, unsigned short* __restrict__ xt,
    unsigned short* __restrict__ wqtb, unsigned short* __restrict__ wktb,
    unsigned short* __restrict__ wvb, float* __restrict__ partials)
{
  const int bid = blockIdx.x;
  const int tid = threadIdx.x;
  if (bid < 6144) {                       // x role: 64l x 32d tile
    __shared__ float tile[64][33];
    __shared__ float pt[8][32];
    const int z = bid / 768, rem = bid % 768;
    const int l0 = (rem / 24) * 64, d0 = (rem % 24) * 32;
    const int tx = tid & 31, ty = tid >> 5;
    const float* xz = x + ((long)z * 2048 + l0) * 768 + d0;
    unsigned short* xbz = xb + ((long)z * 2048 + l0) * 768 + d0;
    float colacc = 0.f;
#pragma unroll
    for (int i = 0; i < 8; ++i) {
      float v = xz[(long)(i * 8 + ty) * 768 + tx];
      tile[i * 8 + ty][tx] = v;
      xbz[(long)(i * 8 + ty) * 768 + tx] = f2bf(v);
      colacc += v;
    }
    pt[ty][tx] = colacc;
    __syncthreads();
    unsigned short* xtz = xt + ((long)z * 768 + d0) * 2048 + l0;
#pragma unroll
    for (int i = 0; i < 4; ++i) {
      int d = i * 8 + ty;
      ushort2 o; o.x = f2bf(tile[2 * tx][d]); o.y = f2bf(tile[2 * tx + 1][d]);
      *(ushort2*)(xtz + (long)d * 2048 + 2 * tx) = o;
    }
    if (ty == 0) {
      float s = 0.f;
#pragma unroll
      for (int t = 0; t < 8; ++t) s += pt[t][tx];
      partials[((long)z * 768 + d0 + tx) * 32 + (l0 >> 6)] = s;
    }
  } else if (bid < 7296) {                // weight transpose (wq, wk)
    __shared__ float tl[32][33];
    int t = bid - 6144;
    const float* W = (t < 576) ? Wq : Wk;
    unsigned short* O = (t < 576) ? wqtb : wktb;
    t = (t >= 576) ? t - 576 : t;
    const int r0 = (t / 24) * 32, c0 = (t % 24) * 32;
    const int tx = tid & 31, ty = tid >> 5;
    for (int i = ty; i < 32; i += 8) tl[i][tx] = W[(long)(r0 + i) * 768 + c0 + tx];
    __syncthreads();
    for (int i = ty; i < 32; i += 8) O[(long)(c0 + i) * 768 + r0 + tx] = f2bf(tl[tx][i]);
  } else {                                // wv cast, 288 blocks x 2048 elems
    const int t = bid - 7296;
    const long i = ((long)t * 256 + tid) * 8;
    float4 v0 = *(const float4*)(Wv + i);
    float4 v1 = *(const float4*)(Wv + i + 4);
    unsigned short o[8];
    o[0] = f2bf(v0.x); o[1] = f2bf(v0.y); o[2] = f2bf(v0.z); o[3] = f2bf(v0.w);
    o[4] = f2bf(v1.x); o[5] = f2bf(v1.y); o[6] = f2bf(v1.z); o[7] = f2bf(v1.w);
    *(ushort8*)(wvb + i) = *(ushort8*)o;
  }
}

// ------------- GEMM core: BK=64, 2-phase, T2 XOR-swizzled LDS ---------------
// SYM=1: also write C[col,row] when bm!=bn (for symmetric outputs)
template<int BIAS_MODE, int OUT_BF16, int SYM>
__device__ __forceinline__ void gemm_core(
    int z, long bm, long bn,
    unsigned short* __restrict__ As, unsigned short* __restrict__ Bs,
    const unsigned short* __restrict__ A, const unsigned short* __restrict__ B,
    const float* __restrict__ bias, const float* __restrict__ b2,
    const float* __restrict__ b3, const float* __restrict__ b4,
    void* __restrict__ Cv,
    int K, int lda, int ldb, int ldc,
    long a_bs, long b_bs, long c_bs, long bias_bs, float scale)
{
  const int tid  = threadIdx.x;
  const int wid  = tid >> 6;
  const int lane = tid & 63;
  const unsigned short* Ab = A + (long)z * a_bs;
  const unsigned short* Bb = B + (long)z * b_bs;

  f32x4 acc[4][4];
#pragma unroll
  for (int r = 0; r < 4; ++r)
#pragma unroll
    for (int c = 0; c < 4; ++c) acc[r][c] = (f32x4){0.f, 0.f, 0.f, 0.f};

  const int srow = lane >> 3;
  const int scol = (((lane & 7) ^ srow)) * 8;
  const int fr   = lane & 15;
  const int xr   = lane & 7;
  const int kq   = lane >> 4;

#define STAGE(p, k0) do { \
  _Pragma("unroll") \
  for (int j_ = 0; j_ < 4; ++j_) { \
    const int r_ = wid * 32 + j_ * 8; \
    const unsigned short* ga_ = Ab + (bm + r_ + srow) * (long)lda + (k0) + scol; \
    __builtin_amdgcn_global_load_lds((gmem_void*)ga_, (lds_void*)(As + (p) * BM * BK + r_ * BK), 16, 0, 0); \
    const unsigned short* gb_ = Bb + (bn + r_ + srow) * (long)ldb + (k0) + scol; \
    __builtin_amdgcn_global_load_lds((gmem_void*)gb_, (lds_void*)(Bs + (p) * BN * BK + r_ * BK), 16, 0, 0); \
  } } while (0)

  const int nt = K / BK;
  STAGE(0, 0);
  __syncthreads();

  for (int t = 0; t < nt; ++t) {
    const int p = t & 1;
    if (t + 1 < nt) STAGE(p ^ 1, (t + 1) * BK);
    __builtin_amdgcn_s_setprio(1);
#pragma unroll
    for (int kk = 0; kk < 2; ++kk) {
      short8 af[4], bfr[4];
#pragma unroll
      for (int r = 0; r < 4; ++r) {
        const int row = (wid >> 1) * 64 + r * 16 + fr;
        af[r] = *(const short8*)(As + p * BM * BK + row * BK + (((kk * 4 + kq) ^ xr) << 3));
      }
#pragma unroll
      for (int c = 0; c < 4; ++c) {
        const int row = (wid & 1) * 64 + c * 16 + fr;
        bfr[c] = *(const short8*)(Bs + p * BN * BK + row * BK + (((kk * 4 + kq) ^ xr) << 3));
      }
#pragma unroll
      for (int r = 0; r < 4; ++r)
#pragma unroll
        for (int c = 0; c < 4; ++c)
          acc[r][c] = __builtin_amdgcn_mfma_f32_16x16x32_bf16(af[r], bfr[c], acc[r][c], 0, 0, 0);
    }
    __builtin_amdgcn_s_setprio(0);
    if (t + 1 < nt) __syncthreads();
  }
#undef STAGE

  const int wr  = (wid >> 1) * 64;
  const int wc  = (wid & 1) * 64;
  const int cr0 = (lane >> 4) * 4;
  const int cc  = lane & 15;
#pragma unroll
  for (int r = 0; r < 4; ++r)
#pragma unroll
    for (int c = 0; c < 4; ++c)
#pragma unroll
      for (int j = 0; j < 4; ++j) {
        long row = bm + wr + r * 16 + cr0 + j;
        long col = bn + wc + c * 16 + cc;
        float v = acc[r][c][j] * scale;
        if (BIAS_MODE == 1) v += bias[z * bias_bs + col];
        else if (BIAS_MODE == 3)
          v += scale * (bias[row] * (b2[z * 768 + col] + 2048.0f * b4[col])
                        + b3[z * 768 + row] * b4[col]);
        long off = (long)z * c_bs + row * (long)ldc + col;
        if (OUT_BF16) {
          ((unsigned short*)Cv)[off] = f2bf(v);
          if (SYM && bm != bn)
            ((unsigned short*)Cv)[(long)z * c_bs + col * (long)ldc + row] = f2bf(v);
        } else {
          ((float*)Cv)[off] = v;
        }
      }
}

// ---- launch 2: G upper-tri (0..167) + F (168..203) + c1,a2 (204..227) + s (228..235)
__global__ __launch_bounds__(256, 2) void gf_k(
    const unsigned short* xt, unsigned short* G,
    const unsigned short* wqtb, const unsigned short* wktb, unsigned short* F,
    const float* bq, const float* bk, const float* partials,
    float* c1v, float* a2v, float* sv)
{
  __shared__ unsigned short lds[2 * (BM + BN) * BK];   // 64 KiB, shared by all roles
  unsigned short* As = lds;
  unsigned short* Bs = lds + 2 * BM * BK;
  const int bid = blockIdx.x, tid = threadIdx.x;
  if (bid < 168) {                        // G: 21 upper-tri tiles x 8 batches
    const int z = bid & 7;
    int t = bid >> 3;
    int by = 0, off = 0, w = 6;
    while (t >= off + w) { off += w; --w; ++by; }
    const int bx = by + (t - off);
    gemm_core<0, 1, 1>(z, (long)by * BM, (long)bx * BN, As, Bs,
        xt, xt, nullptr, nullptr, nullptr, nullptr, G,
        2048, 2048, 2048, 768, 768L * 2048, 768L * 2048, 768L * 768, 0, 1.0f);
  } else if (bid < 204) {                 // F = wqt · wkt^T
    const int t = bid - 168;
    gemm_core<0, 1, 0>(0, (long)(t / 6) * BM, (long)(t % 6) * BN, As, Bs,
        wqtb, wktb, nullptr, nullptr, nullptr, nullptr, F,
        768, 768, 768, 768, 0, 0, 0, 0, 1.0f);
  } else if (bid < 228) {                 // c1[r]=wkt[r,:]·bq ; a2[r]=wqt[r,:]·bk
    const int wid = tid >> 6, lane = tid & 63;
    const int r0 = (bid - 204) * 32;
#pragma unroll
    for (int mi = 0; mi < 8; ++mi) {
      const int r = r0 + wid * 8 + mi;
      float ac = 0.f, aa = 0.f;
      for (int k = lane; k < 768; k += 64) {
        ac += bf2f(wktb[(long)r * 768 + k]) * bq[k];
        aa += bf2f(wqtb[(long)r * 768 + k]) * bk[k];
      }
      ac = wave_red(ac); aa = wave_red(aa);
      if (lane == 0) { c1v[r] = ac; a2v[r] = aa; }
    }
  } else {                                // s[z,d] from partials
    const int z = bid - 228;
    for (int d = tid; d < 768; d += 256) {
      const float* pp = partials + ((long)z * 768 + d) * 32;
      float s = 0.f;
#pragma unroll
      for (int j = 0; j < 32; ++j) s += pp[j];
      sv[z * 768 + d] = s;
    }
  }
}

// ---- launch 3: H = F·G (0..287) + a1/w/g GEMVs (288..863) -------------------
__global__ __launch_bounds__(256, 2) void hv_k(
    const unsigned short* Fb, const unsigned short* G, unsigned short* H,
    const float* Wv, const float* sv, const float* c1v,
    float* a1v, float* wvv, float* gv)
{
  __shared__ unsigned short lds[2 * (BM + BN) * BK];
  unsigned short* As = lds;
  unsigned short* Bs = lds + 2 * BM * BK;
  const int bid = blockIdx.x, tid = threadIdx.x;
  if (bid < 288) {
    const int z = bid & 7, t = bid >> 3;
    gemm_core<0, 1, 0>(z, (long)(t / 6) * BM, (long)(t % 6) * BN, As, Bs,
        Fb, G, nullptr, nullptr, nullptr, nullptr, H,
        768, 768, 768, 768, 0, 768L * 768, 768L * 768, 0, 1.0f);
  } else {
    const int t = bid - 288;              // 0..575
    const int type = t / 192, u = t % 192;
    const int z = u / 24, r0 = (u % 24) * 32;
    const int wid = tid >> 6, lane = tid & 63;
#pragma unroll
    for (int mi = 0; mi < 8; ++mi) {
      const int r = r0 + wid * 8 + mi;
      float a = 0.f;
      if (type == 0) {                    // a1[z,r] = F[r,:]·s[z,:]
        for (int k = lane; k < 768; k += 64)
          a += bf2f(Fb[(long)r * 768 + k]) * sv[z * 768 + k];
      } else if (type == 1) {             // w[z,r] = Wv[r,:]·s[z,:]
        for (int k = lane; k < 768; k += 64)
          a += Wv[(long)r * 768 + k] * sv[z * 768 + k];
      } else {                            // g[z,r] = G[z][r,:]·c1
        const unsigned short* Gz = G + (long)z * 768 * 768;
        for (int k = lane; k < 768; k += 64)
          a += bf2f(Gz[(long)r * 768 + k]) * c1v[k];
      }
      a = wave_red(a);
      if (lane == 0) {
        if (type == 0) a1v[z * 768 + r] = a;
        else if (type == 1) wvv[z * 768 + r] = a;
        else gv[z * 768 + r] = a;
      }
    }
  }
}

// ---- launch 4: Pt GEMM (0..287) + r blocks (288..479) -----------------------
__global__ __launch_bounds__(256, 2) void pt_k(
    const unsigned short* wvb, const unsigned short* H, unsigned short* Pt,
    const float* bv, const float* a1v, const float* wvv, const float* a2v,
    const float* Wv, const float* gv, const float* c1v, const float* sv,
    const float* bq, const float* bk, float* rv)
{
  __shared__ unsigned short lds[2 * (BM + BN) * BK];
  unsigned short* As = lds;
  unsigned short* Bs = lds + 2 * BM * BK;
  const float inv_sqrt_d = 0.036084391824351615f;
  const int bid = blockIdx.x, tid = threadIdx.x;
  if (bid < 288) {
    const int z = bid & 7, t = bid >> 3;
    gemm_core<3, 1, 0>(z, (long)(t / 6) * BM, (long)(t % 6) * BN, As, Bs,
        wvb, H, bv, a1v, wvv, a2v, Pt,
        768, 768, 768, 768, 0, 768L * 768, 768L * 768, 0, inv_sqrt_d);
  } else {
    float* red1 = (float*)lds;            // reuse GEMM LDS (disjoint role)
    float* red2 = red1 + 256;
    const int u = bid - 288;              // 0..191
    const int z = u / 24, r0 = (u % 24) * 32;
    const int wid = tid >> 6, lane = tid & 63;
    float p1 = 0.f, p2 = 0.f;
    for (int d = tid; d < 768; d += 256) {
      p1 += c1v[d] * sv[z * 768 + d];
      p2 += bq[d] * bk[d];
    }
    red1[tid] = p1; red2[tid] = p2;
    __syncthreads();
    for (int st = 128; st > 0; st >>= 1) {
      if (tid < st) { red1[tid] += red1[tid + st]; red2[tid] += red2[tid + st]; }
      __syncthreads();
    }
    const float cs = red1[0], bb = red2[0];
#pragma unroll
    for (int mi = 0; mi < 8; ++mi) {
      const int o = r0 + wid * 8 + mi;
      float a = 0.f;
      for (int k = lane; k < 768; k += 64)
        a += Wv[(long)o * 768 + k] * gv[z * 768 + k];
      a = wave_red(a);
      if (lane == 0)
        rv[z * 768 + o] = inv_sqrt_d *
            (a + cs * bv[o] + bb * (wvv[z * 768 + o] + 2048.0f * bv[o]));
    }
  }
}

// ---- launch 5: out = xb·Pt^T + r -------------------------------------------
__global__ __launch_bounds__(256, 2) void final_k(
    const unsigned short* xb, const unsigned short* Pt, const float* rv, float* out)
{
  __shared__ unsigned short lds[2 * (BM + BN) * BK];
  unsigned short* As = lds;
  unsigned short* Bs = lds + 2 * BM * BK;
  const int z = blockIdx.x & 7, t = blockIdx.x >> 3;
  gemm_core<1, 0, 0>(z, (long)(t / 6) * BM, (long)(t % 6) * BN, As, Bs,
      xb, Pt, rv, nullptr, nullptr, nullptr, out,
      768, 768, 768, 768, 2048L * 768, 768L * 768, 2048L * 768, 768, 1.0f);
}

extern "C" void kernel_launch(void* const* d_in, const int* in_sizes, int n_in,
                              void* d_out, int out_size, void* d_ws, size_t ws_size,
                              hipStream_t stream) {
  const float* x  = (const float*)d_in[0];
  const float* Wq = (const float*)d_in[1];
  const float* bq = (const float*)d_in[2];
  const float* Wk = (const float*)d_in[3];
  const float* bk = (const float*)d_in[4];
  const float* Wv = (const float*)d_in[5];
  const float* bv = (const float*)d_in[6];
  float* out = (float*)d_out;

  const int Bsz = 8, L = 2048, D = 768;
  const long xN = (long)Bsz * L * D;
  const long wN = (long)D * D;
  const long D2 = wN;

  char* ws = (char*)d_ws;
  unsigned short* xt   = (unsigned short*)ws; ws += xN * 2;
  unsigned short* xb   = (unsigned short*)ws; ws += xN * 2;
  unsigned short* wqtb = (unsigned short*)ws; ws += wN * 2;
  unsigned short* wktb = (unsigned short*)ws; ws += wN * 2;
  unsigned short* wvb  = (unsigned short*)ws; ws += wN * 2;
  unsigned short* Fb   = (unsigned short*)ws; ws += wN * 2;
  unsigned short* regA = (unsigned short*)ws; ws += (long)Bsz * D2 * 2;  // G, later Pt
  unsigned short* regB = (unsigned short*)ws; ws += (long)Bsz * D2 * 2;  // H
  float* partials = (float*)ws; ws += (long)Bsz * D * 32 * 4;
  float* sv  = (float*)ws; ws += (long)Bsz * D * 4;
  float* c1v = (float*)ws; ws += (long)D * 4;
  float* a2v = (float*)ws; ws += (long)D * 4;
  float* a1v = (float*)ws; ws += (long)Bsz * D * 4;
  float* wvv = (float*)ws; ws += (long)Bsz * D * 4;
  float* gv  = (float*)ws; ws += (long)Bsz * D * 4;
  float* rv  = (float*)ws; ws += (long)Bsz * D * 4;

  dim3 blk(256);

  preamble<<<dim3(7584), blk, 0, stream>>>(x, Wq, Wk, Wv, xb, xt, wqtb, wktb, wvb, partials);

  gf_k<<<dim3(236), blk, 0, stream>>>(xt, regA, wqtb, wktb, Fb,
                                      bq, bk, partials, c1v, a2v, sv);

  hv_k<<<dim3(864), blk, 0, stream>>>(Fb, regA, regB, Wv, sv, c1v, a1v, wvv, gv);

  pt_k<<<dim3(480), blk, 0, stream>>>(wvb, regB, regA, bv, a1v, wvv, a2v,
                                      Wv, gv, c1v, sv, bq, bk, rv);

  final_k<<<dim3(768), blk, 0, stream>>>(xb, regA, rv, out);

  (void)in_sizes; (void)n_in; (void)out_size; (void)ws_size;
}